// Round 20
// baseline (183.258 us; speedup 1.0000x reference)
//
#include <hip/hip_runtime.h>
#include <math.h>

#define CB 16          // class_bit
#define ALPHA 0.1f
#define LOG2E 1.4426950408889634f
#define LN2F  0.6931471805599453f
#define MAXW 8         // max t-tiles per block
#define N_BS 128       // batch size (fixed by problem)
#define BIT  48        // code length (fixed by problem)
#define UPAD 52        // u row pitch in LDS floats (16B-aligned)

typedef __bf16 bf16x8 __attribute__((ext_vector_type(8)));
typedef float  f32x16 __attribute__((ext_vector_type(16)));

// R19 kernel (48.97 us, absmax 0) with ONE change: the per-tile epilogue's
// serial dependency chains broken by explicit reassociation.
//  - accA was a 64-deep serial fp-add chain per tile (~256 stall cycles that
//    2.2 resident waves/SIMD cannot hide). Now: 4 parallel sub-chains per
//    MFMA result (static-indexed s4[j&3]) + tree combine -> depth ~7.
//  - pp was serial across bt; now per-bt tree products combined pairwise.
// Math is reassociation-only (same tolerance class as existing trees).
__global__ __launch_bounds__(256, 4) void loss_fused(
        const float* __restrict__ u, const float* __restrict__ y,
        const float* __restrict__ w_D,
        const float* __restrict__ U, const float* __restrict__ Yb,
        const int* __restrict__ ind,
        float* __restrict__ partials, float* __restrict__ quant_partials,
        int n_cls, int n_train, int ntile, int GY) {
    __shared__ float smf[N_BS * UPAD + 4 * BIT * CB];  // 38,912 B, reused
    __shared__ int pflag[MAXW * 32];                   // 1,024 B
    float* u_lds   = smf;                    // [N_BS][UPAD]      (phase 0)
    float* wd_lds  = smf + N_BS * UPAD;      // [4][BIT][CB]      (phase 0)
    float* u_slice = smf;                    // [4][N_BS][CB]     (after sync2)

    const int tid  = threadIdx.x;
    const int lane = tid & 63;
    const int wid  = tid >> 6;
    const int bx   = blockIdx.x;
    const int by   = blockIdx.y;
    const int c    = bx * 4 + wid;           // class for this wave
    const int r    = lane & 31;
    const int h    = lane >> 5;
    const int nw   = (ntile - by + GY - 1) / GY;

    // ---- stage u + w_D slice into LDS; init pflag ----
    pflag[tid] = -1;                          // MAXW*32 == 256 == blockDim
    #pragma unroll
    for (int it = 0; it < N_BS * (BIT / 4) / 256; ++it) {   // 6 float4 each
        int f = it * 256 + tid;
        int b = f / (BIT / 4), k4 = f % (BIT / 4);
        *(float4*)&u_lds[b * UPAD + k4 * 4] =
            *(const float4*)&u[(size_t)b * BIT + k4 * 4];
    }
    #pragma unroll
    for (int it = 0; it < 4 * BIT * (CB / 4) / 256; ++it) { // 3 float4 each
        int f = it * 256 + tid;
        int cc = f / (BIT * CB / 4), rest = f % (BIT * CB / 4);
        *(float4*)&wd_lds[cc * BIT * CB + rest * 4] =
            *(const float4*)&w_D[(size_t)(bx * 4 + cc) * BIT * CB + rest * 4];
    }
    __syncthreads();                          // sync1: staging + pflag init

    if (tid < N_BS) {
        int t = ind[tid];
        for (int w = 0; w < nw; ++w) {
            unsigned rl = (unsigned)(t - (by + w * GY) * 32);
            if (rl < 32u) pflag[w * 32 + rl] = tid;
        }
    }

    // ---- phase 0: per-lane u_ slice: accX[j] = u_[X*32+r][c][h*8+j] ----
    float acc0[8] = {0,0,0,0,0,0,0,0};
    float acc1[8] = {0,0,0,0,0,0,0,0};
    float acc2[8] = {0,0,0,0,0,0,0,0};
    float acc3[8] = {0,0,0,0,0,0,0,0};
    {
        const float* __restrict__ wdc = wd_lds + wid * BIT * CB + h * 8;
        for (int k4 = 0; k4 < BIT / 4; ++k4) {
            float4 ub0 = *(const float4*)&u_lds[(0 * 32 + r) * UPAD + k4 * 4];
            float4 ub1 = *(const float4*)&u_lds[(1 * 32 + r) * UPAD + k4 * 4];
            float4 ub2 = *(const float4*)&u_lds[(2 * 32 + r) * UPAD + k4 * 4];
            float4 ub3 = *(const float4*)&u_lds[(3 * 32 + r) * UPAD + k4 * 4];
            #pragma unroll
            for (int kk = 0; kk < 4; ++kk) {
                const float* wrow = wdc + (k4 * 4 + kk) * CB;
                float w8[8];
                float4 wa = *(const float4*)(wrow);
                float4 wb = *(const float4*)(wrow + 4);
                w8[0]=wa.x; w8[1]=wa.y; w8[2]=wa.z; w8[3]=wa.w;
                w8[4]=wb.x; w8[5]=wb.y; w8[6]=wb.z; w8[7]=wb.w;
                float s0 = (&ub0.x)[kk], s1 = (&ub1.x)[kk];
                float s2 = (&ub2.x)[kk], s3 = (&ub3.x)[kk];
                #pragma unroll
                for (int j = 0; j < 8; ++j) {
                    acc0[j] = fmaf(s0, w8[j], acc0[j]);
                    acc1[j] = fmaf(s1, w8[j], acc1[j]);
                    acc2[j] = fmaf(s2, w8[j], acc2[j]);
                    acc3[j] = fmaf(s3, w8[j], acc3[j]);
                }
            }
        }
    }

    // ---- quantization partial (each element exactly once: by==0 only) ----
    if (by == 0) {
        float q = 0.f;
        #pragma unroll
        for (int j = 0; j < 8; ++j) {
            float v, sgn, d;
            v = acc0[j]; sgn = (v>0.f)?1.f:((v<0.f)?-1.f:0.f); d = v-sgn; q = fmaf(d,d,q);
            v = acc1[j]; sgn = (v>0.f)?1.f:((v<0.f)?-1.f:0.f); d = v-sgn; q = fmaf(d,d,q);
            v = acc2[j]; sgn = (v>0.f)?1.f:((v<0.f)?-1.f:0.f); d = v-sgn; q = fmaf(d,d,q);
            v = acc3[j]; sgn = (v>0.f)?1.f:((v<0.f)?-1.f:0.f); d = v-sgn; q = fmaf(d,d,q);
        }
        #pragma unroll
        for (int off = 32; off > 0; off >>= 1) q += __shfl_down(q, off, 64);
        if (lane == 0) quant_partials[bx * 4 + wid] = q;
    }

    // ---- vvec/wvec for this class, in registers (shfl_xor reduce) ----
    float ypc0 = y[(size_t)(0 * 32 + r) * n_cls + c];
    float ypc1 = y[(size_t)(1 * 32 + r) * n_cls + c];
    float ypc2 = y[(size_t)(2 * 32 + r) * n_cls + c];
    float ypc3 = y[(size_t)(3 * 32 + r) * n_cls + c];
    float vv[8], ww[8];
    #pragma unroll
    for (int j = 0; j < 8; ++j) {
        ww[j] = acc0[j] + acc1[j] + acc2[j] + acc3[j];
        vv[j] = ypc0*acc0[j] + ypc1*acc1[j] + ypc2*acc2[j] + ypc3*acc3[j];
    }
    #pragma unroll
    for (int m = 1; m < 32; m <<= 1) {
        #pragma unroll
        for (int j = 0; j < 8; ++j) {
            vv[j] += __shfl_xor(vv[j], m, 64);
            ww[j] += __shfl_xor(ww[j], m, 64);
        }
    }

    // ---- B fragments (pre-scaled by log2e) ----
    bf16x8 B0, B1, B2, B3;
    #pragma unroll
    for (int j = 0; j < 8; ++j) {
        B0[j] = (__bf16)(acc0[j] * LOG2E);
        B1[j] = (__bf16)(acc1[j] * LOG2E);
        B2[j] = (__bf16)(acc2[j] * LOG2E);
        B3[j] = (__bf16)(acc3[j] * LOG2E);
    }

    __syncthreads();                          // sync2: all LDS reads done
    // ---- write f32 u_ slice for patch rows (overwrites staging) ----
    {
        float* dst = u_slice + wid * N_BS * CB + r * CB + h * 8;
        *(float4*)(dst + 0*32*CB)     = make_float4(acc0[0],acc0[1],acc0[2],acc0[3]);
        *(float4*)(dst + 0*32*CB + 4) = make_float4(acc0[4],acc0[5],acc0[6],acc0[7]);
        *(float4*)(dst + 1*32*CB)     = make_float4(acc1[0],acc1[1],acc1[2],acc1[3]);
        *(float4*)(dst + 1*32*CB + 4) = make_float4(acc1[4],acc1[5],acc1[6],acc1[7]);
        *(float4*)(dst + 2*32*CB)     = make_float4(acc2[0],acc2[1],acc2[2],acc2[3]);
        *(float4*)(dst + 2*32*CB + 4) = make_float4(acc2[4],acc2[5],acc2[6],acc2[7]);
        *(float4*)(dst + 3*32*CB)     = make_float4(acc3[0],acc3[1],acc3[2],acc3[3]);
        *(float4*)(dst + 3*32*CB + 4) = make_float4(acc3[4],acc3[5],acc3[6],acc3[7]);
    }
    __syncthreads();                          // sync3: u_slice + pflag ready

    // ---- tile loop with 1-deep U/Yb prefetch (zero barriers) ----
    float acc = 0.f;
    f32x16 zc = {};
    // prefetch tile w=0
    int rc0 = by * 32 + r;
    if (rc0 >= n_train) rc0 = n_train - 1;
    const float* __restrict__ ar0 = U + ((size_t)rc0 * n_cls + c) * CB + h * 8;
    float4 a0c = *(const float4*)(ar0);
    float4 a1c = *(const float4*)(ar0 + 4);
    float  Yvc = Yb[(size_t)rc0 * n_cls + c];

    #pragma unroll 1
    for (int w = 0; w < nw; ++w) {
        // issue next tile's loads first (consumed next iteration)
        float4 a0n = a0c, a1n = a1c; float Yvn = Yvc;
        if (w + 1 < nw) {                      // wave-uniform branch
            int rcn = (by + (w + 1) * GY) * 32 + r;
            if (rcn >= n_train) rcn = n_train - 1;
            const float* __restrict__ arn =
                U + ((size_t)rcn * n_cls + c) * CB + h * 8;
            a0n = *(const float4*)(arn);
            a1n = *(const float4*)(arn + 4);
            Yvn = Yb[(size_t)rcn * n_cls + c];
        }

        const int t0  = (by + w * GY) * 32;
        const int row = t0 + r;
        const int pf  = pflag[w * 32 + r];
        if (pf >= 0) {
            const float* src = u_slice + wid * N_BS * CB + pf * CB + h * 8;
            a0c = *(const float4*)(src);
            a1c = *(const float4*)(src + 4);
            Yvc = y[(size_t)pf * n_cls + c];
        }
        if (row >= n_train) {
            a0c = make_float4(0.f, 0.f, 0.f, 0.f); a1c = a0c; Yvc = 0.f;
        }

        // side dots vs in-register vvec/wvec
        float sv = a0c.x*vv[0] + a0c.y*vv[1] + a0c.z*vv[2] + a0c.w*vv[3]
                 + a1c.x*vv[4] + a1c.y*vv[5] + a1c.z*vv[6] + a1c.w*vv[7];
        float sw = a0c.x*ww[0] + a0c.y*ww[1] + a0c.z*ww[2] + a0c.w*ww[3]
                 + a1c.x*ww[4] + a1c.y*ww[5] + a1c.z*ww[6] + a1c.w*ww[7];

        bf16x8 A;
        A[0] = (__bf16)a0c.x; A[1] = (__bf16)a0c.y;
        A[2] = (__bf16)a0c.z; A[3] = (__bf16)a0c.w;
        A[4] = (__bf16)a1c.x; A[5] = (__bf16)a1c.y;
        A[6] = (__bf16)a1c.z; A[7] = (__bf16)a1c.w;

        // epilogue: per-bt independent partials, combined by tree per tile
        float tA[4];     // per-bt sum |ip'|
        float tP[4];     // per-bt product (1 + 2^-|ip'|), <= 2^16 each
        #pragma unroll
        for (int bt = 0; bt < 4; ++bt) {
            bf16x8 Bf = (bt == 0) ? B0 : (bt == 1) ? B1 : (bt == 2) ? B2 : B3;
            f32x16 D = __builtin_amdgcn_mfma_f32_32x32x16_bf16(A, Bf, zc,
                                                               0, 0, 0);
            float a[16];
            float s4[4] = {0.f, 0.f, 0.f, 0.f};   // 4 parallel |ip| chains
            #pragma unroll
            for (int j = 0; j < 16; ++j) {
                float ipa = fabsf(D[j]);
                a[j] = 1.0f + __builtin_amdgcn_exp2f(-ipa);
                s4[j & 3] += ipa;                  // static index (unrolled)
            }
            #pragma unroll
            for (int s = 1; s < 16; s <<= 1)
                #pragma unroll
                for (int j = 0; j < 16; j += 2 * s) a[j] *= a[j + s];
            tP[bt] = a[0];
            tA[bt] = (s4[0] + s4[1]) + (s4[2] + s4[3]);
        }
        float accA = (tA[0] + tA[1]) + (tA[2] + tA[3]);
        float pp   = (tP[0] * tP[1]) * (tP[2] * tP[3]);  // <= 2^64, f32-safe
        float accL = __builtin_amdgcn_logf(pp);   // v_log_f32 = log2
        acc += LN2F * accL + (0.5f * LN2F) * accA + 0.5f * sw - Yvc * sv;

        a0c = a0n; a1c = a1n; Yvc = Yvn;          // rotate pipeline
    }

    // per-wave reduction only; no block reduce, no sync
    #pragma unroll
    for (int off = 32; off > 0; off >>= 1)
        acc += __shfl_down(acc, off, 64);
    if (lane == 0) {
        int bid = by * gridDim.x + bx;
        partials[bid * 4 + wid] = acc;
    }
}

__global__ __launch_bounds__(256) void finalize_kernel(
        const float* __restrict__ partials, int nblk,
        const float* __restrict__ quant_partials, int n_quant,
        float* __restrict__ out, double pad_corr,
        double like_scale, double quant_scale) {
    double s = 0.0, q = 0.0;
    for (int i = threadIdx.x; i < nblk; i += 256) s += (double)partials[i];
    for (int i = threadIdx.x; i < n_quant; i += 256) q += (double)quant_partials[i];
    #pragma unroll
    for (int off = 32; off > 0; off >>= 1) {
        s += __shfl_down(s, off, 64);
        q += __shfl_down(q, off, 64);
    }
    __shared__ double dred[4][2];
    int lane = threadIdx.x & 63, wid = threadIdx.x >> 6;
    if (lane == 0) { dred[wid][0] = s; dred[wid][1] = q; }
    __syncthreads();
    if (threadIdx.x == 0) {
        double S = dred[0][0] + dred[1][0] + dred[2][0] + dred[3][0];
        double Q = dred[0][1] + dred[1][1] + dred[2][1] + dred[3][1];
        out[0] = (float)((S - pad_corr) * like_scale + Q * quant_scale);
    }
}

extern "C" void kernel_launch(void* const* d_in, const int* in_sizes, int n_in,
                              void* d_out, int out_size, void* d_ws, size_t ws_size,
                              hipStream_t stream) {
    const float* u   = (const float*)d_in[0];
    const float* y   = (const float*)d_in[1];
    const int*   ind = (const int*)d_in[2];
    const float* U   = (const float*)d_in[3];
    const float* Yb  = (const float*)d_in[4];
    const float* w_D = (const float*)d_in[5];

    const int n_bs    = in_sizes[2];             // 128 (== N_BS)
    const int n_cls   = in_sizes[1] / n_bs;      // 100
    const int n_train = in_sizes[4] / n_cls;     // 10000

    const int totalU = n_bs * n_cls * CB;
    const int ntile  = (n_train + 31) / 32;      // 313
    const int GY     = (ntile + MAXW - 1) / MAXW; // 40
    const int gx     = (n_cls + 3) / 4;          // 25
    const int nblk   = GY * gx;                  // 1000 blocks
    const int npart  = nblk * 4;                 // per-wave partials
    const int nquant = gx * 4;                   // 100 (by==0 column only)

    char* ws = (char*)d_ws;
    size_t off = 0;
    float* partials = (float*)(ws + off);        off += (size_t)npart * 4;
    float* quant_partials = (float*)(ws + off);  off += (size_t)nquant * 4;

    loss_fused<<<dim3(gx, GY), 256, 0, stream>>>(
        u, y, w_D, U, Yb, ind, partials, quant_partials,
        n_cls, n_train, ntile, GY);

    const double ln2 = 0.6931471805599453;
    // pad rows: only tiles < ntile are processed -> ntile*32 - n_train = 16
    const double n_pad = (double)((long long)(ntile * 32 - n_train) *
                                  (long long)n_bs * (long long)n_cls);
    const double pad_corr    = ln2 * n_pad;
    const double like_scale  = 1.0 / ((double)n_bs * n_train * n_cls);
    const double quant_scale = (double)ALPHA / (double)totalU;

    finalize_kernel<<<1, 256, 0, stream>>>(partials, npart,
                                           quant_partials, nquant,
                                           (float*)d_out, pad_corr,
                                           like_scale, quant_scale);
}

// Round 21
// 48.591 us; speedup vs baseline: 3.7715x; 3.7715x over previous
//
#include <hip/hip_runtime.h>
#include <math.h>

#define CB 16          // class_bit
#define ALPHA 0.1f
#define LOG2E 1.4426950408889634f
#define LN2F  0.6931471805599453f
#define MAXW 8         // max t-tiles per block
#define N_BS 128       // batch size (fixed by problem)
#define BIT  48        // code length (fixed by problem)
#define UPAD 52        // u row pitch in LDS floats (16B-aligned)

typedef __bf16 bf16x8 __attribute__((ext_vector_type(8)));
typedef float  f32x16 __attribute__((ext_vector_type(16)));

// FINAL: exact R19 kernel (48.97 us, absmax 0.0) — best of 20 rounds.
// R20's chain-reassociation spilled (4 concurrent D-results live -> 386MB
// scratch): the serial accA/pp chains were load-bearing for liveness.
// Lessons encoded: no fences (R6/7), no deep pipelining (R9), minimal live
// state (R10/R20), LDS-staged phase 0 (R14/R18), grid matched to LDS cap
// (R14/R15), serial epilogue chains kept (R20).
__global__ __launch_bounds__(256, 4) void loss_fused(
        const float* __restrict__ u, const float* __restrict__ y,
        const float* __restrict__ w_D,
        const float* __restrict__ U, const float* __restrict__ Yb,
        const int* __restrict__ ind,
        float* __restrict__ partials, float* __restrict__ quant_partials,
        int n_cls, int n_train, int ntile, int GY) {
    __shared__ float smf[N_BS * UPAD + 4 * BIT * CB];  // 38,912 B, reused
    __shared__ int pflag[MAXW * 32];                   // 1,024 B
    float* u_lds   = smf;                    // [N_BS][UPAD]      (phase 0)
    float* wd_lds  = smf + N_BS * UPAD;      // [4][BIT][CB]      (phase 0)
    float* u_slice = smf;                    // [4][N_BS][CB]     (after sync2)

    const int tid  = threadIdx.x;
    const int lane = tid & 63;
    const int wid  = tid >> 6;
    const int bx   = blockIdx.x;
    const int by   = blockIdx.y;
    const int c    = bx * 4 + wid;           // class for this wave
    const int r    = lane & 31;
    const int h    = lane >> 5;
    const int nw   = (ntile - by + GY - 1) / GY;

    // ---- stage u + w_D slice into LDS; init pflag ----
    pflag[tid] = -1;                          // MAXW*32 == 256 == blockDim
    #pragma unroll
    for (int it = 0; it < N_BS * (BIT / 4) / 256; ++it) {   // 6 float4 each
        int f = it * 256 + tid;
        int b = f / (BIT / 4), k4 = f % (BIT / 4);
        *(float4*)&u_lds[b * UPAD + k4 * 4] =
            *(const float4*)&u[(size_t)b * BIT + k4 * 4];
    }
    #pragma unroll
    for (int it = 0; it < 4 * BIT * (CB / 4) / 256; ++it) { // 3 float4 each
        int f = it * 256 + tid;
        int cc = f / (BIT * CB / 4), rest = f % (BIT * CB / 4);
        *(float4*)&wd_lds[cc * BIT * CB + rest * 4] =
            *(const float4*)&w_D[(size_t)(bx * 4 + cc) * BIT * CB + rest * 4];
    }
    __syncthreads();                          // sync1: staging + pflag init

    if (tid < N_BS) {
        int t = ind[tid];
        for (int w = 0; w < nw; ++w) {
            unsigned rl = (unsigned)(t - (by + w * GY) * 32);
            if (rl < 32u) pflag[w * 32 + rl] = tid;
        }
    }

    // ---- phase 0: per-lane u_ slice: accX[j] = u_[X*32+r][c][h*8+j] ----
    float acc0[8] = {0,0,0,0,0,0,0,0};
    float acc1[8] = {0,0,0,0,0,0,0,0};
    float acc2[8] = {0,0,0,0,0,0,0,0};
    float acc3[8] = {0,0,0,0,0,0,0,0};
    {
        const float* __restrict__ wdc = wd_lds + wid * BIT * CB + h * 8;
        for (int k4 = 0; k4 < BIT / 4; ++k4) {
            float4 ub0 = *(const float4*)&u_lds[(0 * 32 + r) * UPAD + k4 * 4];
            float4 ub1 = *(const float4*)&u_lds[(1 * 32 + r) * UPAD + k4 * 4];
            float4 ub2 = *(const float4*)&u_lds[(2 * 32 + r) * UPAD + k4 * 4];
            float4 ub3 = *(const float4*)&u_lds[(3 * 32 + r) * UPAD + k4 * 4];
            #pragma unroll
            for (int kk = 0; kk < 4; ++kk) {
                const float* wrow = wdc + (k4 * 4 + kk) * CB;
                float w8[8];
                float4 wa = *(const float4*)(wrow);
                float4 wb = *(const float4*)(wrow + 4);
                w8[0]=wa.x; w8[1]=wa.y; w8[2]=wa.z; w8[3]=wa.w;
                w8[4]=wb.x; w8[5]=wb.y; w8[6]=wb.z; w8[7]=wb.w;
                float s0 = (&ub0.x)[kk], s1 = (&ub1.x)[kk];
                float s2 = (&ub2.x)[kk], s3 = (&ub3.x)[kk];
                #pragma unroll
                for (int j = 0; j < 8; ++j) {
                    acc0[j] = fmaf(s0, w8[j], acc0[j]);
                    acc1[j] = fmaf(s1, w8[j], acc1[j]);
                    acc2[j] = fmaf(s2, w8[j], acc2[j]);
                    acc3[j] = fmaf(s3, w8[j], acc3[j]);
                }
            }
        }
    }

    // ---- quantization partial (each element exactly once: by==0 only) ----
    if (by == 0) {
        float q = 0.f;
        #pragma unroll
        for (int j = 0; j < 8; ++j) {
            float v, sgn, d;
            v = acc0[j]; sgn = (v>0.f)?1.f:((v<0.f)?-1.f:0.f); d = v-sgn; q = fmaf(d,d,q);
            v = acc1[j]; sgn = (v>0.f)?1.f:((v<0.f)?-1.f:0.f); d = v-sgn; q = fmaf(d,d,q);
            v = acc2[j]; sgn = (v>0.f)?1.f:((v<0.f)?-1.f:0.f); d = v-sgn; q = fmaf(d,d,q);
            v = acc3[j]; sgn = (v>0.f)?1.f:((v<0.f)?-1.f:0.f); d = v-sgn; q = fmaf(d,d,q);
        }
        #pragma unroll
        for (int off = 32; off > 0; off >>= 1) q += __shfl_down(q, off, 64);
        if (lane == 0) quant_partials[bx * 4 + wid] = q;
    }

    // ---- vvec/wvec for this class, in registers (shfl_xor reduce) ----
    float ypc0 = y[(size_t)(0 * 32 + r) * n_cls + c];
    float ypc1 = y[(size_t)(1 * 32 + r) * n_cls + c];
    float ypc2 = y[(size_t)(2 * 32 + r) * n_cls + c];
    float ypc3 = y[(size_t)(3 * 32 + r) * n_cls + c];
    float vv[8], ww[8];
    #pragma unroll
    for (int j = 0; j < 8; ++j) {
        ww[j] = acc0[j] + acc1[j] + acc2[j] + acc3[j];
        vv[j] = ypc0*acc0[j] + ypc1*acc1[j] + ypc2*acc2[j] + ypc3*acc3[j];
    }
    #pragma unroll
    for (int m = 1; m < 32; m <<= 1) {
        #pragma unroll
        for (int j = 0; j < 8; ++j) {
            vv[j] += __shfl_xor(vv[j], m, 64);
            ww[j] += __shfl_xor(ww[j], m, 64);
        }
    }

    // ---- B fragments (pre-scaled by log2e) ----
    bf16x8 B0, B1, B2, B3;
    #pragma unroll
    for (int j = 0; j < 8; ++j) {
        B0[j] = (__bf16)(acc0[j] * LOG2E);
        B1[j] = (__bf16)(acc1[j] * LOG2E);
        B2[j] = (__bf16)(acc2[j] * LOG2E);
        B3[j] = (__bf16)(acc3[j] * LOG2E);
    }

    __syncthreads();                          // sync2: all LDS reads done
    // ---- write f32 u_ slice for patch rows (overwrites staging) ----
    {
        float* dst = u_slice + wid * N_BS * CB + r * CB + h * 8;
        *(float4*)(dst + 0*32*CB)     = make_float4(acc0[0],acc0[1],acc0[2],acc0[3]);
        *(float4*)(dst + 0*32*CB + 4) = make_float4(acc0[4],acc0[5],acc0[6],acc0[7]);
        *(float4*)(dst + 1*32*CB)     = make_float4(acc1[0],acc1[1],acc1[2],acc1[3]);
        *(float4*)(dst + 1*32*CB + 4) = make_float4(acc1[4],acc1[5],acc1[6],acc1[7]);
        *(float4*)(dst + 2*32*CB)     = make_float4(acc2[0],acc2[1],acc2[2],acc2[3]);
        *(float4*)(dst + 2*32*CB + 4) = make_float4(acc2[4],acc2[5],acc2[6],acc2[7]);
        *(float4*)(dst + 3*32*CB)     = make_float4(acc3[0],acc3[1],acc3[2],acc3[3]);
        *(float4*)(dst + 3*32*CB + 4) = make_float4(acc3[4],acc3[5],acc3[6],acc3[7]);
    }
    __syncthreads();                          // sync3: u_slice + pflag ready

    // ---- tile loop with 1-deep U/Yb prefetch (zero barriers) ----
    float acc = 0.f;
    f32x16 zc = {};
    // prefetch tile w=0
    int rc0 = by * 32 + r;
    if (rc0 >= n_train) rc0 = n_train - 1;
    const float* __restrict__ ar0 = U + ((size_t)rc0 * n_cls + c) * CB + h * 8;
    float4 a0c = *(const float4*)(ar0);
    float4 a1c = *(const float4*)(ar0 + 4);
    float  Yvc = Yb[(size_t)rc0 * n_cls + c];

    #pragma unroll 1
    for (int w = 0; w < nw; ++w) {
        // issue next tile's loads first (consumed next iteration)
        float4 a0n = a0c, a1n = a1c; float Yvn = Yvc;
        if (w + 1 < nw) {                      // wave-uniform branch
            int rcn = (by + (w + 1) * GY) * 32 + r;
            if (rcn >= n_train) rcn = n_train - 1;
            const float* __restrict__ arn =
                U + ((size_t)rcn * n_cls + c) * CB + h * 8;
            a0n = *(const float4*)(arn);
            a1n = *(const float4*)(arn + 4);
            Yvn = Yb[(size_t)rcn * n_cls + c];
        }

        const int t0  = (by + w * GY) * 32;
        const int row = t0 + r;
        const int pf  = pflag[w * 32 + r];
        if (pf >= 0) {
            const float* src = u_slice + wid * N_BS * CB + pf * CB + h * 8;
            a0c = *(const float4*)(src);
            a1c = *(const float4*)(src + 4);
            Yvc = y[(size_t)pf * n_cls + c];
        }
        if (row >= n_train) {
            a0c = make_float4(0.f, 0.f, 0.f, 0.f); a1c = a0c; Yvc = 0.f;
        }

        // side dots vs in-register vvec/wvec
        float sv = a0c.x*vv[0] + a0c.y*vv[1] + a0c.z*vv[2] + a0c.w*vv[3]
                 + a1c.x*vv[4] + a1c.y*vv[5] + a1c.z*vv[6] + a1c.w*vv[7];
        float sw = a0c.x*ww[0] + a0c.y*ww[1] + a0c.z*ww[2] + a0c.w*ww[3]
                 + a1c.x*ww[4] + a1c.y*ww[5] + a1c.z*ww[6] + a1c.w*ww[7];

        bf16x8 A;
        A[0] = (__bf16)a0c.x; A[1] = (__bf16)a0c.y;
        A[2] = (__bf16)a0c.z; A[3] = (__bf16)a0c.w;
        A[4] = (__bf16)a1c.x; A[5] = (__bf16)a1c.y;
        A[6] = (__bf16)a1c.z; A[7] = (__bf16)a1c.w;

        float accA = 0.f;    // sum |ip'| this tile
        float pp   = 1.f;    // prod (1 + 2^-|ip'|), 64 factors in (1,2]
        #pragma unroll
        for (int bt = 0; bt < 4; ++bt) {
            bf16x8 Bf = (bt == 0) ? B0 : (bt == 1) ? B1 : (bt == 2) ? B2 : B3;
            f32x16 D = __builtin_amdgcn_mfma_f32_32x32x16_bf16(A, Bf, zc,
                                                               0, 0, 0);
            float a[16];
            #pragma unroll
            for (int j = 0; j < 16; ++j) {
                float ipa = fabsf(D[j]);
                a[j] = 1.0f + __builtin_amdgcn_exp2f(-ipa);
                accA += ipa;
            }
            #pragma unroll
            for (int s = 1; s < 16; s <<= 1)
                #pragma unroll
                for (int j = 0; j < 16; j += 2 * s) a[j] *= a[j + s];
            pp *= a[0];
        }
        float accL = __builtin_amdgcn_logf(pp);   // v_log_f32 = log2
        acc += LN2F * accL + (0.5f * LN2F) * accA + 0.5f * sw - Yvc * sv;

        a0c = a0n; a1c = a1n; Yvc = Yvn;          // rotate pipeline
    }

    // per-wave reduction only; no block reduce, no sync
    #pragma unroll
    for (int off = 32; off > 0; off >>= 1)
        acc += __shfl_down(acc, off, 64);
    if (lane == 0) {
        int bid = by * gridDim.x + bx;
        partials[bid * 4 + wid] = acc;
    }
}

__global__ __launch_bounds__(256) void finalize_kernel(
        const float* __restrict__ partials, int nblk,
        const float* __restrict__ quant_partials, int n_quant,
        float* __restrict__ out, double pad_corr,
        double like_scale, double quant_scale) {
    double s = 0.0, q = 0.0;
    for (int i = threadIdx.x; i < nblk; i += 256) s += (double)partials[i];
    for (int i = threadIdx.x; i < n_quant; i += 256) q += (double)quant_partials[i];
    #pragma unroll
    for (int off = 32; off > 0; off >>= 1) {
        s += __shfl_down(s, off, 64);
        q += __shfl_down(q, off, 64);
    }
    __shared__ double dred[4][2];
    int lane = threadIdx.x & 63, wid = threadIdx.x >> 6;
    if (lane == 0) { dred[wid][0] = s; dred[wid][1] = q; }
    __syncthreads();
    if (threadIdx.x == 0) {
        double S = dred[0][0] + dred[1][0] + dred[2][0] + dred[3][0];
        double Q = dred[0][1] + dred[1][1] + dred[2][1] + dred[3][1];
        out[0] = (float)((S - pad_corr) * like_scale + Q * quant_scale);
    }
}

extern "C" void kernel_launch(void* const* d_in, const int* in_sizes, int n_in,
                              void* d_out, int out_size, void* d_ws, size_t ws_size,
                              hipStream_t stream) {
    const float* u   = (const float*)d_in[0];
    const float* y   = (const float*)d_in[1];
    const int*   ind = (const int*)d_in[2];
    const float* U   = (const float*)d_in[3];
    const float* Yb  = (const float*)d_in[4];
    const float* w_D = (const float*)d_in[5];

    const int n_bs    = in_sizes[2];             // 128 (== N_BS)
    const int n_cls   = in_sizes[1] / n_bs;      // 100
    const int n_train = in_sizes[4] / n_cls;     // 10000

    const int totalU = n_bs * n_cls * CB;
    const int ntile  = (n_train + 31) / 32;      // 313
    const int GY     = (ntile + MAXW - 1) / MAXW; // 40
    const int gx     = (n_cls + 3) / 4;          // 25
    const int nblk   = GY * gx;                  // 1000 blocks
    const int npart  = nblk * 4;                 // per-wave partials
    const int nquant = gx * 4;                   // 100 (by==0 column only)

    char* ws = (char*)d_ws;
    size_t off = 0;
    float* partials = (float*)(ws + off);        off += (size_t)npart * 4;
    float* quant_partials = (float*)(ws + off);  off += (size_t)nquant * 4;

    loss_fused<<<dim3(gx, GY), 256, 0, stream>>>(
        u, y, w_D, U, Yb, ind, partials, quant_partials,
        n_cls, n_train, ntile, GY);

    const double ln2 = 0.6931471805599453;
    // pad rows: only tiles < ntile are processed -> ntile*32 - n_train = 16
    const double n_pad = (double)((long long)(ntile * 32 - n_train) *
                                  (long long)n_bs * (long long)n_cls);
    const double pad_corr    = ln2 * n_pad;
    const double like_scale  = 1.0 / ((double)n_bs * n_train * n_cls);
    const double quant_scale = (double)ALPHA / (double)totalU;

    finalize_kernel<<<1, 256, 0, stream>>>(partials, npart,
                                           quant_partials, nquant,
                                           (float*)d_out, pad_corr,
                                           like_scale, quant_scale);
}